// Round 5
// baseline (107.021 us; speedup 1.0000x reference)
//
#include <hip/hip_runtime.h>
#include <hip/hip_bf16.h>

// out = x + T @ (x @ Wv^T @ Wo^T), T causal uniform average. fp32 B=16,L=4096,H=256.
// W = Wo@Wv bf16; per 64-row block: Y = bf16(x_tile)@W^T (MFMA), in-register causal
// prefix per wave-column, carry z = Op@W^T, scale, bf16 pack back into X-LDS
// (transposed), fully-coalesced epilogue. 256thr/4 waves/33KB LDS -> 4 blocks/CU.

#define B_  16
#define L_  4096
#define H_  256
#define M_  (B_*L_)
#define CH  64
#define CHROWS 64
#define BM 64

typedef short short4v __attribute__((ext_vector_type(4)));
typedef short short8  __attribute__((ext_vector_type(8)));
typedef float f32x4   __attribute__((ext_vector_type(4)));

__device__ __forceinline__ unsigned short f2bf(float f) {
  unsigned int u = __builtin_bit_cast(unsigned int, f);
  u += 0x7fffu + ((u >> 16) & 1u);
  return (unsigned short)(u >> 16);
}
__device__ __forceinline__ float bf2f(unsigned short s) {
  return __builtin_bit_cast(float, ((unsigned int)s) << 16);
}

// ---------------- K1: W = Wo @ Wv -> bf16 [H][H] ----------------
__global__ void fuse_w_kernel(const float* __restrict__ Wv,
                              const float* __restrict__ Wo,
                              unsigned short* __restrict__ Wbf) {
  __shared__ float wo[H_];
  int h = blockIdx.x, t = threadIdx.x;
  wo[t] = Wo[h*H_ + t];
  __syncthreads();
  float acc = 0.f;
  #pragma unroll 8
  for (int m = 0; m < H_; ++m) acc += wo[m] * Wv[m*H_ + t];
  Wbf[h*H_ + t] = f2bf(acc);
}

// ---------------- K2: per-64-row-chunk column sums ----------------
__global__ void partial_kernel(const float* __restrict__ x, float* __restrict__ P) {
  int c = blockIdx.x, b = blockIdx.y, t = threadIdx.x;
  const float* p = x + ((size_t)(b*L_ + c*CHROWS))*H_ + t;
  float s = 0.f;
  #pragma unroll 8
  for (int r = 0; r < CHROWS; ++r) s += p[(size_t)r*H_];
  P[(b*CH + c)*H_ + t] = s;
}

// ---------------- K3: exclusive scan of chunk sums ----------------
__global__ void scan_kernel(const float* __restrict__ P, float* __restrict__ O) {
  int b = blockIdx.x, t = threadIdx.x;
  float run = 0.f;
  #pragma unroll
  for (int c = 0; c < CH; ++c) {
    int idx = (b*CH + c)*H_ + t;
    O[idx] = run;
    run += P[idx];
  }
}

// ---------------- K4: main fused kernel ----------------
// 1024 blocks x 256 threads (4 waves). Wave w: cols [w*64, w*64+64), rows all 64.
// LDS: [0,32768) X bf16 [64][256] XOR-swizzled (reused for packed-Y after GEMM)
//      [32768,33792) zbuf f32[256]
__global__ __launch_bounds__(256, 4) void main_kernel(
    const float* __restrict__ x,
    const unsigned short* __restrict__ Wbf,
    const float* __restrict__ Op,          // [M_/64][H] exclusive 64-row prefixes
    float* __restrict__ out) {
  __shared__ __align__(16) char smem[33792];
  float* zbuf = (float*)(smem + 32768);

  const int tid = threadIdx.x;
  const int lane = tid & 63, wave = tid >> 6;
  const int rowBase = blockIdx.x * BM;
  const float* xb = x + (size_t)rowBase * H_;

  // ---- stage X tile: 16 coalesced float4 loads (issued first) ----
  float4 xv[16];
  #pragma unroll
  for (int j = 0; j < 16; ++j) {
    int idx = tid + j*256;                 // (row, col4): row=idx>>6, col4=idx&63
    xv[j] = *(const float4*)(xb + (idx >> 6)*H_ + (idx & 63)*4);
  }

  // ---- z-dot (overlaps x-load latency): z[c] = Op_row . W[c], 8-way ILP ----
  {
    const float* op = Op + (size_t)blockIdx.x * H_;
    const unsigned short* wr = Wbf + (size_t)tid * H_;
    float ze[8] = {0,0,0,0,0,0,0,0};
    #pragma unroll
    for (int kk = 0; kk < 32; ++kk) {
      short8 w8 = *(const short8*)(wr + kk*8);
      #pragma unroll
      for (int e = 0; e < 8; ++e) ze[e] += op[kk*8 + e] * bf2f((unsigned short)w8[e]);
    }
    zbuf[tid] = ((ze[0]+ze[1]) + (ze[2]+ze[3])) + ((ze[4]+ze[5]) + (ze[6]+ze[7]));
  }

  // ---- convert + swizzled LDS write ----
  #pragma unroll
  for (int j = 0; j < 16; ++j) {
    int idx = tid + j*256;
    int row = idx >> 6, col4 = idx & 63;
    short4v s;
    s[0] = (short)f2bf(xv[j].x); s[1] = (short)f2bf(xv[j].y);
    s[2] = (short)f2bf(xv[j].z); s[3] = (short)f2bf(xv[j].w);
    *(short4v*)(smem + row*512 + ((col4*8) ^ ((row & 7) << 4))) = s;
  }
  __syncthreads();

  // ---- GEMM: acc = Xbf @ W^T. Wave tile 64 rows x 64 cols, K=256 ----
  const int lrow = lane & 15, g = lane >> 4;
  f32x4 acc[4][4] = {};
  #pragma unroll
  for (int k0 = 0; k0 < 4; ++k0) {
    #pragma unroll
    for (int ks = 0; ks < 2; ++ks) {
      short8 bfr[4], af[4];
      #pragma unroll
      for (int n = 0; n < 4; ++n) {
        int wrow = wave*64 + n*16 + lrow;
        bfr[n] = *(const short8*)(Wbf + (size_t)wrow*H_ + k0*64 + ks*32 + g*8);
      }
      #pragma unroll
      for (int i = 0; i < 4; ++i) {
        int ar = i*16 + lrow;
        int cb = (k0*128 + ks*64 + g*16) ^ ((ar & 7) << 4);
        af[i] = *(const short8*)(smem + ar*512 + cb);
      }
      #pragma unroll
      for (int i = 0; i < 4; ++i)
        #pragma unroll
        for (int n = 0; n < 4; ++n)
          acc[i][n] = __builtin_amdgcn_mfma_f32_16x16x32_bf16(af[i], bfr[n], acc[i][n], 0, 0, 0);
    }
  }

  // ---- causal prefix + carry + scale (registers only) ----
  #pragma unroll
  for (int n = 0; n < 4; ++n) {
    float base = zbuf[wave*64 + n*16 + lrow];
    float run = 0.f;
    #pragma unroll
    for (int i = 0; i < 4; ++i) {
      f32x4 a = acc[i][n];
      a[1] += a[0]; a[2] += a[1]; a[3] += a[2];     // q-inclusive
      float Bv = a[3];
      float v = Bv, t;
      t = __shfl_up(v, 16); if (lane >= 16) v += t;
      t = __shfl_up(v, 32); if (lane >= 32) v += t; // g-inclusive of 4-blocks
      float gex = v - Bv;
      float tot = __shfl(v, lrow + 48);             // 16-row column total
      float addv = gex + run + base;
      #pragma unroll
      for (int q = 0; q < 4; ++q) {
        int row = rowBase + i*16 + g*4 + q;
        float scale = 1.0f / (float)((row & (L_-1)) + 1);
        a[q] = (a[q] + addv) * scale;
      }
      acc[i][n] = a;
      run += tot;
    }
  }
  __syncthreads();                                   // all X reads done

  // ---- pack scaled Y (bf16) transposed into X-LDS ----
  #pragma unroll
  for (int i = 0; i < 4; ++i)
    #pragma unroll
    for (int n = 0; n < 4; ++n)
      #pragma unroll
      for (int q = 0; q < 4; ++q) {
        int row = i*16 + g*4 + q;
        int col = wave*64 + n*16 + lrow;
        *(unsigned short*)(smem + row*512 + ((col*2) ^ ((row & 7) << 4))) =
            f2bf(acc[i][n][q]);
      }
  __syncthreads();

  // ---- coalesced epilogue: out = x + Y ----
  float* ob = out + (size_t)rowBase * H_;
  #pragma unroll
  for (int j = 0; j < 16; ++j) {
    int idx = tid + j*256;
    int row = idx >> 6, col4 = idx & 63;
    short4v s = *(const short4v*)(smem + row*512 + ((col4*8) ^ ((row & 7) << 4)));
    float4 xr = *(const float4*)(xb + row*H_ + col4*4);
    float4 o;
    o.x = xr.x + bf2f((unsigned short)s[0]);
    o.y = xr.y + bf2f((unsigned short)s[1]);
    o.z = xr.z + bf2f((unsigned short)s[2]);
    o.w = xr.w + bf2f((unsigned short)s[3]);
    *(float4*)(ob + row*H_ + col4*4) = o;
  }
}

extern "C" void kernel_launch(void* const* d_in, const int* in_sizes, int n_in,
                              void* d_out, int out_size, void* d_ws, size_t ws_size,
                              hipStream_t stream) {
  const float* x  = (const float*)d_in[0];
  const float* Wv = (const float*)d_in[1];
  const float* Wo = (const float*)d_in[2];
  float* out = (float*)d_out;

  char* ws = (char*)d_ws;
  unsigned short* Wbf = (unsigned short*)ws;                    // 128KB
  float* P  = (float*)(ws + 131072);                            // 1MB
  float* Op = (float*)(ws + 131072 + 1048576);                  // 1MB

  hipLaunchKernelGGL(fuse_w_kernel,  dim3(H_),     dim3(H_), 0, stream, Wv, Wo, Wbf);
  hipLaunchKernelGGL(partial_kernel, dim3(CH, B_), dim3(H_), 0, stream, x, P);
  hipLaunchKernelGGL(scan_kernel,    dim3(B_),     dim3(H_), 0, stream, P, Op);
  hipLaunchKernelGGL(main_kernel,    dim3(M_/BM),  dim3(256), 0, stream,
                     x, Wbf, Op, out);
}

// Round 6
// 98.720 us; speedup vs baseline: 1.0841x; 1.0841x over previous
//
#include <hip/hip_runtime.h>
#include <hip/hip_bf16.h>

// out = x + T @ (x @ Wv^T @ Wo^T), T causal uniform average. fp32 B=16,L=4096,H=256.
// W = Wo@Wv bf16; per 64-row block: Y = bf16(x_tile)@W^T (MFMA), in-register causal
// prefix per wave-column, carry z = Op@W^T, scale, bf16 pack back into X-LDS
// (transposed), fully-coalesced epilogue.
// R6 change: __launch_bounds__(256) with NO min-wave cap (R2-R5 were all
// register-spilling under forced 64-128 VGPR budgets -> scratch thrash), and
// no persistent staging array.

#define B_  16
#define L_  4096
#define H_  256
#define M_  (B_*L_)
#define CH  64
#define CHROWS 64
#define BM 64

typedef short short4v __attribute__((ext_vector_type(4)));
typedef short short8  __attribute__((ext_vector_type(8)));
typedef float f32x4   __attribute__((ext_vector_type(4)));

__device__ __forceinline__ unsigned short f2bf(float f) {
  unsigned int u = __builtin_bit_cast(unsigned int, f);
  u += 0x7fffu + ((u >> 16) & 1u);
  return (unsigned short)(u >> 16);
}
__device__ __forceinline__ float bf2f(unsigned short s) {
  return __builtin_bit_cast(float, ((unsigned int)s) << 16);
}

// ---------------- K1: W = Wo @ Wv -> bf16 [H][H] ----------------
__global__ void fuse_w_kernel(const float* __restrict__ Wv,
                              const float* __restrict__ Wo,
                              unsigned short* __restrict__ Wbf) {
  __shared__ float wo[H_];
  int h = blockIdx.x, t = threadIdx.x;
  wo[t] = Wo[h*H_ + t];
  __syncthreads();
  float acc = 0.f;
  #pragma unroll 8
  for (int m = 0; m < H_; ++m) acc += wo[m] * Wv[m*H_ + t];
  Wbf[h*H_ + t] = f2bf(acc);
}

// ---------------- K2: per-64-row-chunk column sums ----------------
__global__ void partial_kernel(const float* __restrict__ x, float* __restrict__ P) {
  int c = blockIdx.x, b = blockIdx.y, t = threadIdx.x;
  const float* p = x + ((size_t)(b*L_ + c*CHROWS))*H_ + t;
  float s = 0.f;
  #pragma unroll 8
  for (int r = 0; r < CHROWS; ++r) s += p[(size_t)r*H_];
  P[(b*CH + c)*H_ + t] = s;
}

// ---------------- K3: exclusive scan of chunk sums ----------------
__global__ void scan_kernel(const float* __restrict__ P, float* __restrict__ O) {
  int b = blockIdx.x, t = threadIdx.x;
  float run = 0.f;
  #pragma unroll
  for (int c = 0; c < CH; ++c) {
    int idx = (b*CH + c)*H_ + t;
    O[idx] = run;
    run += P[idx];
  }
}

// ---------------- K4: main fused kernel ----------------
// 1024 blocks x 256 threads (4 waves). Wave w: cols [w*64, w*64+64), rows all 64.
// LDS: [0,32768) X bf16 [64][256] XOR-swizzled (reused for packed-Y after GEMM)
//      [32768,33792) zbuf f32[256]
__global__ __launch_bounds__(256) void main_kernel(
    const float* __restrict__ x,
    const unsigned short* __restrict__ Wbf,
    const float* __restrict__ Op,          // [M_/64][H] exclusive 64-row prefixes
    float* __restrict__ out) {
  __shared__ __align__(16) char smem[33792];
  float* zbuf = (float*)(smem + 32768);

  const int tid = threadIdx.x;
  const int lane = tid & 63, wave = tid >> 6;
  const int rowBase = blockIdx.x * BM;
  const float* xb = x + (size_t)rowBase * H_;

  // ---- stage X tile: coalesced float4 load -> bf16 -> swizzled LDS ----
  #pragma unroll
  for (int j = 0; j < 16; ++j) {
    int idx = tid + j*256;                 // row = idx>>6, col4 = idx&63
    int row = idx >> 6, col4 = idx & 63;
    float4 v = *(const float4*)(xb + row*H_ + col4*4);
    short4v s;
    s[0] = (short)f2bf(v.x); s[1] = (short)f2bf(v.y);
    s[2] = (short)f2bf(v.z); s[3] = (short)f2bf(v.w);
    *(short4v*)(smem + row*512 + ((col4*8) ^ ((row & 7) << 4))) = s;
  }

  // ---- z-dot (overlaps staging latency): z[c] = Op_row . W[c], 8-way ILP ----
  {
    const float* op = Op + (size_t)blockIdx.x * H_;
    const unsigned short* wr = Wbf + (size_t)tid * H_;
    float ze[8] = {0,0,0,0,0,0,0,0};
    #pragma unroll
    for (int kk = 0; kk < 32; ++kk) {
      short8 w8 = *(const short8*)(wr + kk*8);
      #pragma unroll
      for (int e = 0; e < 8; ++e) ze[e] += op[kk*8 + e] * bf2f((unsigned short)w8[e]);
    }
    zbuf[tid] = ((ze[0]+ze[1]) + (ze[2]+ze[3])) + ((ze[4]+ze[5]) + (ze[6]+ze[7]));
  }
  __syncthreads();

  // ---- GEMM: acc = Xbf @ W^T. Wave tile 64 rows x 64 cols, K=256 ----
  const int lrow = lane & 15, g = lane >> 4;
  f32x4 acc[4][4] = {};
  #pragma unroll
  for (int k0 = 0; k0 < 4; ++k0) {
    #pragma unroll
    for (int ks = 0; ks < 2; ++ks) {
      short8 bfr[4], af[4];
      #pragma unroll
      for (int n = 0; n < 4; ++n) {
        int wrow = wave*64 + n*16 + lrow;
        bfr[n] = *(const short8*)(Wbf + (size_t)wrow*H_ + k0*64 + ks*32 + g*8);
      }
      #pragma unroll
      for (int i = 0; i < 4; ++i) {
        int ar = i*16 + lrow;
        int cb = (k0*128 + ks*64 + g*16) ^ ((ar & 7) << 4);
        af[i] = *(const short8*)(smem + ar*512 + cb);
      }
      #pragma unroll
      for (int i = 0; i < 4; ++i)
        #pragma unroll
        for (int n = 0; n < 4; ++n)
          acc[i][n] = __builtin_amdgcn_mfma_f32_16x16x32_bf16(af[i], bfr[n], acc[i][n], 0, 0, 0);
    }
  }

  // ---- causal prefix + carry + scale (registers only) ----
  #pragma unroll
  for (int n = 0; n < 4; ++n) {
    float base = zbuf[wave*64 + n*16 + lrow];
    float run = 0.f;
    #pragma unroll
    for (int i = 0; i < 4; ++i) {
      f32x4 a = acc[i][n];
      a[1] += a[0]; a[2] += a[1]; a[3] += a[2];     // q-inclusive
      float Bv = a[3];
      float v = Bv, t;
      t = __shfl_up(v, 16); if (lane >= 16) v += t;
      t = __shfl_up(v, 32); if (lane >= 32) v += t; // g-inclusive of 4-blocks
      float gex = v - Bv;
      float tot = __shfl(v, lrow + 48);             // 16-row column total
      float addv = gex + run + base;
      #pragma unroll
      for (int q = 0; q < 4; ++q) {
        int row = rowBase + i*16 + g*4 + q;
        float scale = 1.0f / (float)((row & (L_-1)) + 1);
        a[q] = (a[q] + addv) * scale;
      }
      acc[i][n] = a;
      run += tot;
    }
  }
  __syncthreads();                                   // all X reads done

  // ---- pack scaled Y (bf16) transposed into X-LDS ----
  #pragma unroll
  for (int i = 0; i < 4; ++i)
    #pragma unroll
    for (int n = 0; n < 4; ++n)
      #pragma unroll
      for (int q = 0; q < 4; ++q) {
        int row = i*16 + g*4 + q;
        int col = wave*64 + n*16 + lrow;
        *(unsigned short*)(smem + row*512 + ((col*2) ^ ((row & 7) << 4))) =
            f2bf(acc[i][n][q]);
      }
  __syncthreads();

  // ---- coalesced epilogue: out = x + Y ----
  float* ob = out + (size_t)rowBase * H_;
  #pragma unroll
  for (int j = 0; j < 16; ++j) {
    int idx = tid + j*256;
    int row = idx >> 6, col4 = idx & 63;
    short4v s = *(const short4v*)(smem + row*512 + ((col4*8) ^ ((row & 7) << 4)));
    float4 xr = *(const float4*)(xb + row*H_ + col4*4);
    float4 o;
    o.x = xr.x + bf2f((unsigned short)s[0]);
    o.y = xr.y + bf2f((unsigned short)s[1]);
    o.z = xr.z + bf2f((unsigned short)s[2]);
    o.w = xr.w + bf2f((unsigned short)s[3]);
    *(float4*)(ob + row*H_ + col4*4) = o;
  }
}

extern "C" void kernel_launch(void* const* d_in, const int* in_sizes, int n_in,
                              void* d_out, int out_size, void* d_ws, size_t ws_size,
                              hipStream_t stream) {
  const float* x  = (const float*)d_in[0];
  const float* Wv = (const float*)d_in[1];
  const float* Wo = (const float*)d_in[2];
  float* out = (float*)d_out;

  char* ws = (char*)d_ws;
  unsigned short* Wbf = (unsigned short*)ws;                    // 128KB
  float* P  = (float*)(ws + 131072);                            // 1MB
  float* Op = (float*)(ws + 131072 + 1048576);                  // 1MB

  hipLaunchKernelGGL(fuse_w_kernel,  dim3(H_),     dim3(H_), 0, stream, Wv, Wo, Wbf);
  hipLaunchKernelGGL(partial_kernel, dim3(CH, B_), dim3(H_), 0, stream, x, P);
  hipLaunchKernelGGL(scan_kernel,    dim3(B_),     dim3(H_), 0, stream, P, Op);
  hipLaunchKernelGGL(main_kernel,    dim3(M_/BM),  dim3(256), 0, stream,
                     x, Wbf, Op, out);
}